// Round 1
// baseline (310.172 us; speedup 1.0000x reference)
//
#include <hip/hip_runtime.h>
#include <hip/hip_bf16.h>
#include <stdint.h>

// Problem constants: B=2, S=T=2048, D=2048, N=8 heads, K=1 kv head, H=256
#define BB 2
#define SS 2048
#define DD 2048
#define NHEAD 8
#define HH 256

typedef __bf16 bf16_t;
typedef __bf16 bf16x8 __attribute__((ext_vector_type(8)));
typedef __bf16 bf16x4v __attribute__((ext_vector_type(4)));
typedef float f32x4 __attribute__((ext_vector_type(4)));

__device__ static inline void gload_lds16(const void* g, void* l) {
  __builtin_amdgcn_global_load_lds(
      (__attribute__((address_space(1))) void*)(g),
      (__attribute__((address_space(3))) void*)(l), 16, 0, 0);
}

// ---------------- x -> bf16 ----------------
__global__ void cvt_x_kernel(const float* __restrict__ x, bf16_t* __restrict__ xb) {
  size_t i = ((size_t)blockIdx.x * 256 + threadIdx.x) * 4;
  float4 v = *(const float4*)(x + i);
  bf16x4v o = {(bf16_t)v.x, (bf16_t)v.y, (bf16_t)v.z, (bf16_t)v.w};
  *(bf16x4v*)(xb + i) = o;
}

// ---------------- tiled transpose+convert: out[c][r] = (bf16)in[r][c] ----------------
// in: [R][C] fp32 (batch via blockIdx.z), out: [C][R] bf16
__global__ void transpose_cvt(const float* __restrict__ in, bf16_t* __restrict__ out,
                              int R, int C) {
  __shared__ float tile[32][33];
  int bx = blockIdx.x, by = blockIdx.y, z = blockIdx.z;
  in  += (size_t)z * R * C;
  out += (size_t)z * R * C;
  int tx = threadIdx.x & 31, ty = threadIdx.x >> 5;  // 32x8
#pragma unroll
  for (int k = 0; k < 4; ++k) {
    int r = by * 32 + ty + k * 8, c = bx * 32 + tx;
    tile[ty + k * 8][tx] = in[(size_t)r * C + c];
  }
  __syncthreads();
#pragma unroll
  for (int k = 0; k < 4; ++k) {
    int c = bx * 32 + ty + k * 8, r = by * 32 + tx;
    out[(size_t)c * R + r] = (bf16_t)tile[tx][ty + k * 8];
  }
}

// ---------------- GEMM: C[M][Nc] = A[M][Kd] * BT[Nc][Kd]^T  (bf16 in, fp32 acc) ----------------
template <int OUT_F32>
__global__ __launch_bounds__(256) void gemm_bt(const bf16_t* __restrict__ A,
                                               const bf16_t* __restrict__ BT,
                                               void* __restrict__ C,
                                               int M, int Nc, int Kd) {
  __shared__ bf16_t At[128 * 64];
  __shared__ bf16_t Bt[128 * 64];
  const int ntiles = Nc >> 7;
  int bid = blockIdx.x;
  int mt = bid / ntiles, ntb = bid % ntiles;
  int t = threadIdx.x;
  int lane = t & 63, w = t >> 6;
  int wm = w >> 1, wn = w & 1;
  int l15 = lane & 15, lg = lane >> 4;
  f32x4 acc[4][4] = {};
  for (int kt = 0; kt < Kd; kt += 64) {
#pragma unroll
    for (int r = 0; r < 4; ++r) {
      int o = t * 16 + r * 4096;     // byte offset into 16KB tile
      int row = o >> 7;              // 128B per row (64 bf16)
      int cb = o & 127;
      gload_lds16(A + (size_t)(mt * 128 + row) * Kd + kt + (cb >> 1), (char*)At + o);
      gload_lds16(BT + (size_t)(ntb * 128 + row) * Kd + kt + (cb >> 1), (char*)Bt + o);
    }
    __syncthreads();
#pragma unroll
    for (int ks = 0; ks < 2; ++ks) {
      bf16x8 af[4], bfr[4];
#pragma unroll
      for (int i = 0; i < 4; ++i) {
        af[i]  = *(const bf16x8*)(At + (wm * 64 + i * 16 + l15) * 64 + ks * 32 + lg * 8);
        bfr[i] = *(const bf16x8*)(Bt + (wn * 64 + i * 16 + l15) * 64 + ks * 32 + lg * 8);
      }
#pragma unroll
      for (int i = 0; i < 4; ++i)
#pragma unroll
        for (int j = 0; j < 4; ++j)
          acc[i][j] = __builtin_amdgcn_mfma_f32_16x16x32_bf16(af[i], bfr[j], acc[i][j], 0, 0, 0);
    }
    __syncthreads();
  }
#pragma unroll
  for (int i = 0; i < 4; ++i)
#pragma unroll
    for (int j = 0; j < 4; ++j) {
      int row = mt * 128 + wm * 64 + i * 16 + lg * 4;
      int col = ntb * 128 + wn * 64 + j * 16 + l15;
#pragma unroll
      for (int v = 0; v < 4; ++v) {
        if (OUT_F32)
          ((float*)C)[(size_t)(row + v) * Nc + col] = acc[i][j][v];
        else
          ((bf16_t*)C)[(size_t)(row + v) * Nc + col] = (bf16_t)acc[i][j][v];
      }
    }
}

// ---------------- RoPE (in-place) on q [4096][2048] and k (kv cols 0..255) ----------------
__global__ void rope_kernel(bf16_t* __restrict__ q, bf16_t* __restrict__ kvb,
                            const int* __restrict__ positions) {
  int idx = blockIdx.x * 256 + threadIdx.x;
  const int QP = 4096 * 8 * 128;
  int i, row;
  bf16_t *p1, *p2;
  float scl;
  if (idx < QP) {
    i = idx & 127;
    int nh = (idx >> 7) & 7;
    row = idx >> 10;
    p1 = q + (size_t)row * 2048 + nh * 256 + i;
    p2 = p1 + 128;
    scl = 0.0625f;  // H^-0.5 = 1/16
  } else {
    int kk = idx - QP;
    if (kk >= 4096 * 128) return;
    i = kk & 127;
    row = kk >> 7;
    p1 = kvb + (size_t)row * 512 + i;
    p2 = p1 + 128;
    scl = 1.0f;
  }
  float pos = (float)positions[row];
  // timescale = 10000^(i/128); ang = pos / timescale
  float ang = pos * __expf(-(float)i * (9.2103403719761836f / 128.f));
  float s = sinf(ang), c = cosf(ang);
  float x1 = (float)*p1, x2 = (float)*p2;
  *p1 = (bf16_t)((x1 * c - x2 * s) * scl);
  *p2 = (bf16_t)((x2 * c + x1 * s) * scl);
}

// ---------------- V transpose: vt[b][h][s] = kv[(b*S+s)][256+h] ----------------
__global__ void vt_kernel(const bf16_t* __restrict__ kvb, bf16_t* __restrict__ vt) {
  int idx = blockIdx.x * 256 + threadIdx.x;  // b*H*S + h*S + s
  int s = idx & 2047, h = (idx >> 11) & 255, b = idx >> 19;
  vt[idx] = kvb[((size_t)(b * SS + s)) * 512 + 256 + h];
}

// ---------------- Flash attention ----------------
// grid: B*N*16 pairs; block 256 thr (4 waves x 16 q-rows); handles qt and 31-qt.
__global__ __launch_bounds__(256) void flash_kernel(const bf16_t* __restrict__ q,
                                                    const bf16_t* __restrict__ kvb,
                                                    const bf16_t* __restrict__ vtg,
                                                    bf16_t* __restrict__ enc) {
  __shared__ bf16_t Kt[64 * 256];    // [s][h], 512B rows, XOR-swizzled
  __shared__ bf16_t Vt[256 * 64];    // [h][s], 128B rows, XOR-swizzled
  __shared__ bf16_t Pl[4][16 * 64];  // per-wave P, 128B rows, XOR-swizzled
  int bid = blockIdx.x;
  int pair = bid & 15, n = (bid >> 4) & 7, b = bid >> 7;
  int t = threadIdx.x, lane = t & 63, w = t >> 6;
  int l15 = lane & 15, lg = lane >> 4;
  bf16_t* P = Pl[w];
  for (int half = 0; half < 2; ++half) {
    int qt = half ? (31 - pair) : pair;
    bf16x8 qf[8];
    const bf16_t* qrow = q + ((size_t)(b * SS + qt * 64 + w * 16 + l15)) * 2048 + n * 256;
#pragma unroll
    for (int kk = 0; kk < 8; ++kk) qf[kk] = *(const bf16x8*)(qrow + kk * 32 + lg * 8);
    f32x4 accO[16];
#pragma unroll
    for (int ht = 0; ht < 16; ++ht) accO[ht] = f32x4{0.f, 0.f, 0.f, 0.f};
    float m_r[4], l_r[4];
#pragma unroll
    for (int v = 0; v < 4; ++v) { m_r[v] = -1e30f; l_r[v] = 0.f; }
    for (int kt = 0; kt <= qt; ++kt) {
      // stage K tile [64][256] (rows=512B) with pre-swizzled global source
#pragma unroll
      for (int r = 0; r < 8; ++r) {
        int o = t * 16 + r * 4096;
        int row = o >> 9, cb = (o & 511) ^ ((row & 7) << 4);
        gload_lds16(kvb + ((size_t)(b * SS + kt * 64 + row)) * 512 + (cb >> 1), (char*)Kt + o);
      }
      // stage V^T tile [256][64] (rows=128B)
#pragma unroll
      for (int r = 0; r < 8; ++r) {
        int o = t * 16 + r * 4096;
        int row = o >> 7, cb = (o & 127) ^ ((row & 7) << 4);
        gload_lds16(vtg + ((size_t)(b * HH + row)) * 2048 + kt * 64 + (cb >> 1), (char*)Vt + o);
      }
      __syncthreads();
      // QK^T: 16 q-rows x 64 s
      f32x4 sc4[4];
#pragma unroll
      for (int ntt = 0; ntt < 4; ++ntt) sc4[ntt] = f32x4{0.f, 0.f, 0.f, 0.f};
#pragma unroll
      for (int kk = 0; kk < 8; ++kk) {
        int byte0 = (kk * 32 + lg * 8) * 2;
#pragma unroll
        for (int ntt = 0; ntt < 4; ++ntt) {
          int srow = ntt * 16 + l15;
          bf16x8 kf = *(const bf16x8*)((const char*)Kt + srow * 512 + (byte0 ^ ((srow & 7) << 4)));
          sc4[ntt] = __builtin_amdgcn_mfma_f32_16x16x32_bf16(qf[kk], kf, sc4[ntt], 0, 0, 0);
        }
      }
      if (kt == qt) {  // causal mask on diagonal tile
#pragma unroll
        for (int ntt = 0; ntt < 4; ++ntt) {
          int s_g = kt * 64 + ntt * 16 + l15;
          int r_g = qt * 64 + w * 16 + lg * 4;
#pragma unroll
          for (int v = 0; v < 4; ++v)
            if (s_g > r_g + v) sc4[ntt][v] = -1e30f;
        }
      }
      // online softmax (wave-parallel, 16-lane groups)
#pragma unroll
      for (int v = 0; v < 4; ++v) {
        float pm = fmaxf(fmaxf(sc4[0][v], sc4[1][v]), fmaxf(sc4[2][v], sc4[3][v]));
        pm = fmaxf(pm, __shfl_xor(pm, 1));
        pm = fmaxf(pm, __shfl_xor(pm, 2));
        pm = fmaxf(pm, __shfl_xor(pm, 4));
        pm = fmaxf(pm, __shfl_xor(pm, 8));
        float mnew = fmaxf(m_r[v], pm);
        float scale = __expf(m_r[v] - mnew);
        float rs = 0.f;
#pragma unroll
        for (int ntt = 0; ntt < 4; ++ntt) {
          float p = __expf(sc4[ntt][v] - mnew);
          sc4[ntt][v] = p;
          rs += p;
        }
        rs += __shfl_xor(rs, 1);
        rs += __shfl_xor(rs, 2);
        rs += __shfl_xor(rs, 4);
        rs += __shfl_xor(rs, 8);
        l_r[v] = l_r[v] * scale + rs;
        m_r[v] = mnew;
#pragma unroll
        for (int ht = 0; ht < 16; ++ht) accO[ht][v] *= scale;
      }
      // P -> LDS (bf16, swizzled), per-wave private
#pragma unroll
      for (int ntt = 0; ntt < 4; ++ntt)
#pragma unroll
        for (int v = 0; v < 4; ++v) {
          int row = lg * 4 + v, col = ntt * 16 + l15;
          *(bf16_t*)((char*)P + row * 128 + ((col * 2) ^ ((row & 7) << 4))) = (bf16_t)sc4[ntt][v];
        }
      // PV: O += P[16x64] * V[64x256]
#pragma unroll
      for (int ks = 0; ks < 2; ++ks) {
        int pb = (ks * 32 + lg * 8) * 2;
        bf16x8 pf = *(const bf16x8*)((const char*)P + l15 * 128 + (pb ^ ((l15 & 7) << 4)));
#pragma unroll
        for (int ht = 0; ht < 16; ++ht) {
          int vrow = ht * 16 + l15;
          bf16x8 vf = *(const bf16x8*)((const char*)Vt + vrow * 128 + (pb ^ ((vrow & 7) << 4)));
          accO[ht] = __builtin_amdgcn_mfma_f32_16x16x32_bf16(pf, vf, accO[ht], 0, 0, 0);
        }
      }
      __syncthreads();
    }
    // epilogue: normalize and store enc
#pragma unroll
    for (int ht = 0; ht < 16; ++ht) {
#pragma unroll
      for (int v = 0; v < 4; ++v) {
        float o = accO[ht][v] / l_r[v];
        enc[((size_t)(b * SS + qt * 64 + w * 16 + lg * 4 + v)) * 2048 + n * 256 + ht * 16 + l15] =
            (bf16_t)o;
      }
    }
  }
}

extern "C" void kernel_launch(void* const* d_in, const int* in_sizes, int n_in,
                              void* d_out, int out_size, void* d_ws, size_t ws_size,
                              hipStream_t stream) {
  const float* x = (const float*)d_in[0];
  const int* positions = (const int*)d_in[1];
  // d_in[2] = attn_mask (causal tril) — implemented analytically
  const float* qw = (const float*)d_in[3];
  const float* kvw = (const float*)d_in[4];
  const float* outw = (const float*)d_in[5];

  char* ws = (char*)d_ws;
  if (ws_size < (size_t)75497472) return;  // need ~72MB scratch
  bf16_t* xb     = (bf16_t*)(ws);             // [4096][2048]
  bf16_t* qwbt   = (bf16_t*)(ws + 16777216);  // [2048(n,h)][2048(d)]
  bf16_t* kvwbt  = (bf16_t*)(ws + 25165824);  // [512(c,h)][2048(d)]
  bf16_t* outwbt = (bf16_t*)(ws + 27262976);  // [2048(d)][2048(n,h)]
  bf16_t* qb     = (bf16_t*)(ws + 35651584);  // [4096][2048]
  bf16_t* kvb    = (bf16_t*)(ws + 52428800);  // [4096][512]
  bf16_t* vtg    = (bf16_t*)(ws + 56623104);  // [2][256][2048]
  bf16_t* encb   = (bf16_t*)(ws + 58720256);  // [4096][2048]

  cvt_x_kernel<<<8192, 256, 0, stream>>>(x, xb);
  transpose_cvt<<<dim3(8, 64, 8), 256, 0, stream>>>(qw, qwbt, 2048, 256);
  transpose_cvt<<<dim3(8, 64, 2), 256, 0, stream>>>(kvw, kvwbt, 2048, 256);
  transpose_cvt<<<dim3(64, 64, 1), 256, 0, stream>>>(outw, outwbt, 2048, 2048);
  gemm_bt<0><<<512, 256, 0, stream>>>(xb, qwbt, qb, 4096, 2048, 2048);
  gemm_bt<0><<<128, 256, 0, stream>>>(xb, kvwbt, kvb, 4096, 512, 2048);
  rope_kernel<<<18432, 256, 0, stream>>>(qb, kvb, positions);
  vt_kernel<<<4096, 256, 0, stream>>>(kvb, vtg);
  flash_kernel<<<256, 256, 0, stream>>>(qb, kvb, vtg, encb);
  gemm_bt<1><<<512, 256, 0, stream>>>(encb, outwbt, d_out, 4096, 2048, 2048);
}

// Round 2
// 280.893 us; speedup vs baseline: 1.1042x; 1.1042x over previous
//
#include <hip/hip_runtime.h>
#include <hip/hip_bf16.h>
#include <stdint.h>

// Problem constants: B=2, S=T=2048, D=2048, N=8 heads, K=1 kv head, H=256
#define BB 2
#define SS 2048
#define DD 2048
#define NHEAD 8
#define HH 256

typedef __bf16 bf16_t;
typedef __bf16 bf16x8 __attribute__((ext_vector_type(8)));
typedef __bf16 bf16x4v __attribute__((ext_vector_type(4)));
typedef float f32x4 __attribute__((ext_vector_type(4)));

__device__ static inline void gload_lds16(const void* g, void* l) {
  __builtin_amdgcn_global_load_lds(
      (__attribute__((address_space(1))) void*)(g),
      (__attribute__((address_space(3))) void*)(l), 16, 0, 0);
}

// ---------------- x -> bf16 ----------------
__global__ void cvt_x_kernel(const float* __restrict__ x, bf16_t* __restrict__ xb) {
  size_t i = ((size_t)blockIdx.x * 256 + threadIdx.x) * 4;
  float4 v = *(const float4*)(x + i);
  bf16x4v o = {(bf16_t)v.x, (bf16_t)v.y, (bf16_t)v.z, (bf16_t)v.w};
  *(bf16x4v*)(xb + i) = o;
}

// ---------------- tiled transpose+convert: out[c][r] = (bf16)in[r][c] ----------------
__global__ void transpose_cvt(const float* __restrict__ in, bf16_t* __restrict__ out,
                              int R, int C) {
  __shared__ float tile[32][33];
  int bx = blockIdx.x, by = blockIdx.y, z = blockIdx.z;
  in  += (size_t)z * R * C;
  out += (size_t)z * R * C;
  int tx = threadIdx.x & 31, ty = threadIdx.x >> 5;  // 32x8
#pragma unroll
  for (int k = 0; k < 4; ++k) {
    int r = by * 32 + ty + k * 8, c = bx * 32 + tx;
    tile[ty + k * 8][tx] = in[(size_t)r * C + c];
  }
  __syncthreads();
#pragma unroll
  for (int k = 0; k < 4; ++k) {
    int c = bx * 32 + ty + k * 8, r = by * 32 + tx;
    out[(size_t)c * R + r] = (bf16_t)tile[tx][ty + k * 8];
  }
}

// ---------------- GEMM: C[M][Nc] = A[M][Kd] * BT[Nc][Kd]^T  (bf16 in, fp32 acc) ----------------
template <int OUT_F32>
__global__ __launch_bounds__(256) void gemm_bt(const bf16_t* __restrict__ A,
                                               const bf16_t* __restrict__ BT,
                                               void* __restrict__ C,
                                               int M, int Nc, int Kd) {
  __shared__ bf16_t At[128 * 64];
  __shared__ bf16_t Bt[128 * 64];
  const int ntiles = Nc >> 7;
  int bid = blockIdx.x;
  int mt = bid / ntiles, ntb = bid % ntiles;
  int t = threadIdx.x;
  int lane = t & 63, w = t >> 6;
  int wm = w >> 1, wn = w & 1;
  int l15 = lane & 15, lg = lane >> 4;
  f32x4 acc[4][4] = {};
  for (int kt = 0; kt < Kd; kt += 64) {
#pragma unroll
    for (int r = 0; r < 4; ++r) {
      int o = t * 16 + r * 4096;     // byte offset into 16KB tile
      int row = o >> 7;              // 128B per row (64 bf16)
      int cb = o & 127;
      gload_lds16(A + (size_t)(mt * 128 + row) * Kd + kt + (cb >> 1), (char*)At + o);
      gload_lds16(BT + (size_t)(ntb * 128 + row) * Kd + kt + (cb >> 1), (char*)Bt + o);
    }
    __syncthreads();
#pragma unroll
    for (int ks = 0; ks < 2; ++ks) {
      bf16x8 af[4], bfr[4];
#pragma unroll
      for (int i = 0; i < 4; ++i) {
        af[i]  = *(const bf16x8*)(At + (wm * 64 + i * 16 + l15) * 64 + ks * 32 + lg * 8);
        bfr[i] = *(const bf16x8*)(Bt + (wn * 64 + i * 16 + l15) * 64 + ks * 32 + lg * 8);
      }
      __builtin_amdgcn_s_setprio(1);
#pragma unroll
      for (int i = 0; i < 4; ++i)
#pragma unroll
        for (int j = 0; j < 4; ++j)
          acc[i][j] = __builtin_amdgcn_mfma_f32_16x16x32_bf16(af[i], bfr[j], acc[i][j], 0, 0, 0);
      __builtin_amdgcn_s_setprio(0);
    }
    __syncthreads();
  }
#pragma unroll
  for (int i = 0; i < 4; ++i)
#pragma unroll
    for (int j = 0; j < 4; ++j) {
      int row = mt * 128 + wm * 64 + i * 16 + lg * 4;
      int col = ntb * 128 + wn * 64 + j * 16 + l15;
#pragma unroll
      for (int v = 0; v < 4; ++v) {
        if (OUT_F32)
          ((float*)C)[(size_t)(row + v) * Nc + col] = acc[i][j][v];
        else
          ((bf16_t*)C)[(size_t)(row + v) * Nc + col] = (bf16_t)acc[i][j][v];
      }
    }
}

// ---------------- RoPE (in-place) on fused qkv [4096][2560] ----------------
__global__ void rope_kernel(bf16_t* __restrict__ qkv, const int* __restrict__ positions) {
  int idx = blockIdx.x * 256 + threadIdx.x;
  const int QP = 4096 * 8 * 128;
  int i, row;
  bf16_t *p1, *p2;
  float scl;
  if (idx < QP) {
    i = idx & 127;
    int nh = (idx >> 7) & 7;
    row = idx >> 10;
    p1 = qkv + (size_t)row * 2560 + nh * 256 + i;
    p2 = p1 + 128;
    scl = 0.0625f;  // H^-0.5 = 1/16
  } else {
    int kk = idx - QP;
    if (kk >= 4096 * 128) return;
    i = kk & 127;
    row = kk >> 7;
    p1 = qkv + (size_t)row * 2560 + 2048 + i;
    p2 = p1 + 128;
    scl = 1.0f;
  }
  float pos = (float)positions[row];
  float ang = pos * __expf(-(float)i * (9.2103403719761836f / 128.f));
  float s = sinf(ang), c = cosf(ang);
  float x1 = (float)*p1, x2 = (float)*p2;
  *p1 = (bf16_t)((x1 * c - x2 * s) * scl);
  *p2 = (bf16_t)((x2 * c + x1 * s) * scl);
}

// ---------------- V transpose (LDS-tiled): vt[b][h][s] = qkv[(b*S+s)][2304+h] ----------------
__global__ void vt_kernel(const bf16_t* __restrict__ qkv, bf16_t* __restrict__ vt) {
  __shared__ bf16_t tile[32][34];
  int bx = blockIdx.x;  // s-tile (64)
  int by = blockIdx.y;  // h-tile (8)
  int b = blockIdx.z;
  int tx = threadIdx.x & 31, ty = threadIdx.x >> 5;
#pragma unroll
  for (int k = 0; k < 4; ++k) {
    int s = bx * 32 + ty + k * 8, h = by * 32 + tx;
    tile[ty + k * 8][tx] = qkv[((size_t)(b * SS + s)) * 2560 + 2304 + h];
  }
  __syncthreads();
#pragma unroll
  for (int k = 0; k < 4; ++k) {
    int h = by * 32 + ty + k * 8, s = bx * 32 + tx;
    vt[((size_t)(b * HH + h)) * 2048 + s] = tile[tx][ty + k * 8];
  }
}

// ---------------- Flash attention ----------------
// grid 512: bid<256 -> qt = bid&15 ascending; bid>=256 -> qt = 31-(bid&15).
// Round-robin dispatch puts bid and bid+256 on the same CU -> complementary work,
// 2 blocks/CU resident (LDS 72KB, VGPR<=256) -> cross-block latency hiding.
__global__ __launch_bounds__(256, 2) void flash_kernel(const bf16_t* __restrict__ qkv,
                                                       const bf16_t* __restrict__ vtg,
                                                       bf16_t* __restrict__ enc) {
  __shared__ bf16_t Kt[64 * 256];    // [s][h], 512B rows, XOR-swizzled
  __shared__ bf16_t Vt[256 * 64];    // [h][s], 128B rows, XOR-swizzled
  __shared__ bf16_t Pl[4][16 * 64];  // per-wave P, 128B rows, XOR-swizzled
  int bid = blockIdx.x;
  int grp = bid & 255, half = bid >> 8;
  int b = grp >> 7, n = (grp >> 4) & 7, q4 = grp & 15;
  int qt = half ? (31 - q4) : q4;
  int t = threadIdx.x, lane = t & 63, w = t >> 6;
  int l15 = lane & 15, lg = lane >> 4;
  bf16_t* P = Pl[w];
  bf16x8 qf[8];
  const bf16_t* qrow = qkv + ((size_t)(b * SS + qt * 64 + w * 16 + l15)) * 2560 + n * 256;
#pragma unroll
  for (int kk = 0; kk < 8; ++kk) qf[kk] = *(const bf16x8*)(qrow + kk * 32 + lg * 8);
  f32x4 accO[16];
#pragma unroll
  for (int ht = 0; ht < 16; ++ht) accO[ht] = f32x4{0.f, 0.f, 0.f, 0.f};
  float m_r[4], l_r[4];
#pragma unroll
  for (int v = 0; v < 4; ++v) { m_r[v] = -1e30f; l_r[v] = 0.f; }
  for (int kt = 0; kt <= qt; ++kt) {
    // stage K tile [64][256] (rows=512B) with pre-swizzled global source
#pragma unroll
    for (int r = 0; r < 8; ++r) {
      int o = t * 16 + r * 4096;
      int row = o >> 9, cb = (o & 511) ^ ((row & 7) << 4);
      gload_lds16(qkv + ((size_t)(b * SS + kt * 64 + row)) * 2560 + 2048 + (cb >> 1),
                  (char*)Kt + o);
    }
    // stage V^T tile [256][64] (rows=128B)
#pragma unroll
    for (int r = 0; r < 8; ++r) {
      int o = t * 16 + r * 4096;
      int row = o >> 7, cb = (o & 127) ^ ((row & 7) << 4);
      gload_lds16(vtg + ((size_t)(b * HH + row)) * 2048 + kt * 64 + (cb >> 1), (char*)Vt + o);
    }
    __syncthreads();
    // QK^T: 16 q-rows x 64 s
    f32x4 sc4[4];
#pragma unroll
    for (int ntt = 0; ntt < 4; ++ntt) sc4[ntt] = f32x4{0.f, 0.f, 0.f, 0.f};
    __builtin_amdgcn_s_setprio(1);
#pragma unroll
    for (int kk = 0; kk < 8; ++kk) {
      int byte0 = (kk * 32 + lg * 8) * 2;
#pragma unroll
      for (int ntt = 0; ntt < 4; ++ntt) {
        int srow = ntt * 16 + l15;
        bf16x8 kf = *(const bf16x8*)((const char*)Kt + srow * 512 + (byte0 ^ ((srow & 7) << 4)));
        sc4[ntt] = __builtin_amdgcn_mfma_f32_16x16x32_bf16(qf[kk], kf, sc4[ntt], 0, 0, 0);
      }
    }
    __builtin_amdgcn_s_setprio(0);
    if (kt == qt) {  // causal mask on diagonal tile
#pragma unroll
      for (int ntt = 0; ntt < 4; ++ntt) {
        int s_g = kt * 64 + ntt * 16 + l15;
        int r_g = qt * 64 + w * 16 + lg * 4;
#pragma unroll
        for (int v = 0; v < 4; ++v)
          if (s_g > r_g + v) sc4[ntt][v] = -1e30f;
      }
    }
    // online softmax (wave-parallel, 16-lane groups)
#pragma unroll
    for (int v = 0; v < 4; ++v) {
      float pm = fmaxf(fmaxf(sc4[0][v], sc4[1][v]), fmaxf(sc4[2][v], sc4[3][v]));
      pm = fmaxf(pm, __shfl_xor(pm, 1));
      pm = fmaxf(pm, __shfl_xor(pm, 2));
      pm = fmaxf(pm, __shfl_xor(pm, 4));
      pm = fmaxf(pm, __shfl_xor(pm, 8));
      float mnew = fmaxf(m_r[v], pm);
      float scale = __expf(m_r[v] - mnew);
      float rs = 0.f;
#pragma unroll
      for (int ntt = 0; ntt < 4; ++ntt) {
        float p = __expf(sc4[ntt][v] - mnew);
        sc4[ntt][v] = p;
        rs += p;
      }
      rs += __shfl_xor(rs, 1);
      rs += __shfl_xor(rs, 2);
      rs += __shfl_xor(rs, 4);
      rs += __shfl_xor(rs, 8);
      l_r[v] = l_r[v] * scale + rs;
      m_r[v] = mnew;
#pragma unroll
      for (int ht = 0; ht < 16; ++ht) accO[ht][v] *= scale;
    }
    // P -> LDS (bf16, swizzled), per-wave private
#pragma unroll
    for (int ntt = 0; ntt < 4; ++ntt)
#pragma unroll
      for (int v = 0; v < 4; ++v) {
        int row = lg * 4 + v, col = ntt * 16 + l15;
        *(bf16_t*)((char*)P + row * 128 + ((col * 2) ^ ((row & 7) << 4))) = (bf16_t)sc4[ntt][v];
      }
    // PV: O += P[16x64] * V[64x256]
    __builtin_amdgcn_s_setprio(1);
#pragma unroll
    for (int ks = 0; ks < 2; ++ks) {
      int pb = (ks * 32 + lg * 8) * 2;
      bf16x8 pf = *(const bf16x8*)((const char*)P + l15 * 128 + (pb ^ ((l15 & 7) << 4)));
#pragma unroll
      for (int ht = 0; ht < 16; ++ht) {
        int vrow = ht * 16 + l15;
        bf16x8 vf = *(const bf16x8*)((const char*)Vt + vrow * 128 + (pb ^ ((vrow & 7) << 4)));
        accO[ht] = __builtin_amdgcn_mfma_f32_16x16x32_bf16(pf, vf, accO[ht], 0, 0, 0);
      }
    }
    __builtin_amdgcn_s_setprio(0);
    __syncthreads();
  }
  // epilogue: normalize and store enc
#pragma unroll
  for (int ht = 0; ht < 16; ++ht) {
#pragma unroll
    for (int v = 0; v < 4; ++v) {
      float o = accO[ht][v] / l_r[v];
      enc[((size_t)(b * SS + qt * 64 + w * 16 + lg * 4 + v)) * 2048 + n * 256 + ht * 16 + l15] =
          (bf16_t)o;
    }
  }
}

extern "C" void kernel_launch(void* const* d_in, const int* in_sizes, int n_in,
                              void* d_out, int out_size, void* d_ws, size_t ws_size,
                              hipStream_t stream) {
  const float* x = (const float*)d_in[0];
  const int* positions = (const int*)d_in[1];
  // d_in[2] = attn_mask (causal tril) — implemented analytically
  const float* qw = (const float*)d_in[3];
  const float* kvw = (const float*)d_in[4];
  const float* outw = (const float*)d_in[5];

  char* ws = (char*)d_ws;
  if (ws_size < (size_t)75497472) return;  // need ~72MB scratch
  bf16_t* xb      = (bf16_t*)(ws);             // [4096][2048]
  bf16_t* qkvwbt  = (bf16_t*)(ws + 16777216);  // [2560][2048]: q rows 0..2047, k 2048..2303, v 2304..2559
  bf16_t* outwbt  = (bf16_t*)(ws + 27262976);  // [2048][2048]
  bf16_t* qkvb    = (bf16_t*)(ws + 35651584);  // [4096][2560]
  bf16_t* vtg     = (bf16_t*)(ws + 56623104);  // [2][256][2048]
  bf16_t* encb    = (bf16_t*)(ws + 58720256);  // [4096][2048]

  cvt_x_kernel<<<8192, 256, 0, stream>>>(x, xb);
  transpose_cvt<<<dim3(8, 64, 8), 256, 0, stream>>>(qw, qkvwbt, 2048, 256);
  transpose_cvt<<<dim3(8, 64, 2), 256, 0, stream>>>(kvw, qkvwbt + (size_t)2048 * 2048, 2048, 256);
  transpose_cvt<<<dim3(64, 64, 1), 256, 0, stream>>>(outw, outwbt, 2048, 2048);
  gemm_bt<0><<<640, 256, 0, stream>>>(xb, qkvwbt, qkvb, 4096, 2560, 2048);
  rope_kernel<<<18432, 256, 0, stream>>>(qkvb, positions);
  vt_kernel<<<dim3(64, 8, 2), 256, 0, stream>>>(qkvb, vtg);
  flash_kernel<<<512, 256, 0, stream>>>(qkvb, vtg, encb);
  gemm_bt<1><<<512, 256, 0, stream>>>(encb, outwbt, d_out, 4096, 2048, 2048);
}